// Round 2
// baseline (836.523 us; speedup 1.0000x reference)
//
#include <hip/hip_runtime.h>
#include <hip/hip_bf16.h>

typedef __attribute__((ext_vector_type(8))) short short8;
typedef __attribute__((ext_vector_type(4))) float f32x4;

#define NTOP 1000
#define NPAD 1024
#define KC   256
#define MROWS 40000

static __device__ __forceinline__ unsigned short f2bf(float x) {
    union { float f; unsigned u; } v; v.f = x;
    unsigned r = (v.u + 0x7FFFu + ((v.u >> 16) & 1u)) >> 16;
    return (unsigned short)r;
}

// Kernel 1: colsum[j] += sum over a 32-row slab of nw. colsum pre-zeroed by memset.
__global__ void k_prep(const float* __restrict__ nw,
                       float* __restrict__ colsum) {
    int j  = blockIdx.x * 256 + threadIdx.x;
    int i0 = blockIdx.y * 32;
    if (j < NTOP) {
        float s = 0.f;
        int iend = min(i0 + 32, NTOP);
        for (int i = i0; i < iend; ++i) s += nw[(size_t)i * NTOP + j];
        atomicAdd(colsum + j, s);
    }
}

// Kernel 2: Bpad[j,k] = bf16(V[j,k]*colsum[j] + 0.1*noise[j,k]), zero-padded to NPAD rows.
__global__ void k_vj(const float* __restrict__ V,
                     const float* __restrict__ noise,
                     const float* __restrict__ colsum,
                     unsigned short* __restrict__ Bpad) {
    int idx = blockIdx.x * 256 + threadIdx.x;   // over NPAD*KC
    int j = idx >> 8;
    float x = 0.f;
    if (j < NTOP) x = V[idx] * colsum[j] + 0.1f * noise[idx];
    Bpad[idx] = f2bf(x);
}

// Kernel 3: fused U_emb + GEMM(A@B^T) + sigmoid + masked Normal log-prob + reduce.
// Block = 256 threads = 4 waves. All 4 waves share the same 16 M-rows (A-frags
// rebuilt per wave; U lines served from L1/L2), each wave covers a disjoint
// quarter of the N range (4 of 16 ns-chunks of 64 columns).
__global__ __launch_bounds__(256, 8) void k_main(
    const float* __restrict__ U, const float* __restrict__ w5,
    const float* __restrict__ b1, const unsigned short* __restrict__ Bpad,
    const float* __restrict__ R, const int* __restrict__ C,
    float* __restrict__ out)
{
    const int tid  = threadIdx.x;
    const int wave = tid >> 6;
    const int l    = tid & 63;
    const int lm = l & 15;       // A row within tile / B row (n) within tile
    const int lq = l >> 4;       // quad: k-offset selector
    const int m0 = blockIdx.x << 4;

    const float w0 = w5[0], w1 = w5[1], w2 = w5[2], w3 = w5[3], w4 = w5[4];
    const float bb = b1[0];

    // ---- Build 8 A-fragments: U_emb[m0+lm, k] in bf16, k = s*32 + lq*8 + j ----
    short8 afr[8];
    {
        const int m = m0 + lm;
        #pragma unroll
        for (int s = 0; s < 8; ++s) {
            const float4* up4 = reinterpret_cast<const float4*>(
                U + (size_t)(m * KC + s * 32 + lq * 8) * 5);
            float u[40];
            #pragma unroll
            for (int i = 0; i < 10; ++i) {
                float4 t = up4[i];
                u[i*4+0] = t.x; u[i*4+1] = t.y; u[i*4+2] = t.z; u[i*4+3] = t.w;
            }
            union { short8 v; unsigned short us[8]; } pk;
            #pragma unroll
            for (int j = 0; j < 8; ++j) {
                float e = u[j*5+0]*w0 + u[j*5+1]*w1 + u[j*5+2]*w2
                        + u[j*5+3]*w3 + u[j*5+4]*w4 + bb;
                pk.us[j] = f2bf(e);
            }
            afr[s] = pk.v;
        }
    }

    const int kb = lq * 8;
    float lpsum = 0.f;

    for (int ns = wave * 4; ns < wave * 4 + 4; ++ns) {
        const int n0 = ns << 6;
        f32x4 acc[4];
        #pragma unroll
        for (int t = 0; t < 4; ++t) acc[t] = (f32x4){0.f, 0.f, 0.f, 0.f};

        #pragma unroll
        for (int s = 0; s < 8; ++s) {
            #pragma unroll
            for (int t = 0; t < 4; ++t) {
                const short8 bfr = *reinterpret_cast<const short8*>(
                    Bpad + (size_t)(n0 + t * 16 + lm) * KC + s * 32 + kb);
                acc[t] = __builtin_amdgcn_mfma_f32_16x16x32_bf16(afr[s], bfr, acc[t], 0, 0, 0);
            }
        }

        // Epilogue: C/D layout n = lane&15, m = (lane>>4)*4 + reg
        #pragma unroll
        for (int t = 0; t < 4; ++t) {
            const int n = n0 + t * 16 + lm;
            if (n < NTOP) {
                const size_t base = (size_t)(m0 + lq * 4) * NTOP + n;
                #pragma unroll
                for (int r = 0; r < 4; ++r) {
                    float x   = acc[t][r];
                    float muv = 1.f / (1.f + __expf(-x));
                    float d   = R[base + (size_t)r * NTOP] - muv;
                    float lp  = -50.f * d * d + 1.3836465597893728f;
                    if (C[base + (size_t)r * NTOP] == 1) lpsum += lp;
                }
            }
        }
    }

    #pragma unroll
    for (int off = 32; off > 0; off >>= 1) lpsum += __shfl_down(lpsum, off);
    if (l == 0) atomicAdd(out, lpsum);
}

extern "C" void kernel_launch(void* const* d_in, const int* in_sizes, int n_in,
                              void* d_out, int out_size, void* d_ws, size_t ws_size,
                              hipStream_t stream) {
    const float* V     = (const float*)d_in[1];
    const float* R     = (const float*)d_in[2];
    const float* nw    = (const float*)d_in[3];
    const float* U     = (const float*)d_in[4];
    const float* w5    = (const float*)d_in[5];
    const float* b1    = (const float*)d_in[6];
    const float* noise = (const float*)d_in[7];
    const int*   C     = (const int*)d_in[8];
    float* out = (float*)d_out;

    float* colsum        = (float*)d_ws;
    unsigned short* Bpad = (unsigned short*)((char*)d_ws + 8192);

    hipMemsetAsync(colsum, 0, NTOP * sizeof(float), stream);
    hipMemsetAsync(out, 0, sizeof(float), stream);
    hipLaunchKernelGGL(k_prep, dim3(4, 32), dim3(256), 0, stream, nw, colsum);
    hipLaunchKernelGGL(k_vj, dim3(NPAD * KC / 256), dim3(256), 0, stream,
                       V, noise, colsum, Bpad);
    hipLaunchKernelGGL(k_main, dim3(MROWS / 16), dim3(256), 0, stream,
                       U, w5, b1, Bpad, R, C, out);
}

// Round 3
// 718.676 us; speedup vs baseline: 1.1640x; 1.1640x over previous
//
#include <hip/hip_runtime.h>
#include <hip/hip_bf16.h>

typedef __attribute__((ext_vector_type(8))) short short8;
typedef __attribute__((ext_vector_type(4))) float f32x4;

#define NTOP 1000
#define NPAD 1024
#define KC   256
#define MROWS 40000

static __device__ __forceinline__ unsigned short f2bf(float x) {
    union { float f; unsigned u; } v; v.f = x;
    unsigned r = (v.u + 0x7FFFu + ((v.u >> 16) & 1u)) >> 16;
    return (unsigned short)r;
}

// Kernel 1: colsum[j] += sum over an 8-row slab of nw. colsum pre-zeroed by memset.
__global__ void k_prep(const float* __restrict__ nw,
                       float* __restrict__ colsum) {
    int j  = blockIdx.x * 256 + threadIdx.x;
    int i0 = blockIdx.y * 8;
    if (j < NTOP) {
        float s = 0.f;
        int iend = min(i0 + 8, NTOP);
        for (int i = i0; i < iend; ++i) s += nw[(size_t)i * NTOP + j];
        atomicAdd(colsum + j, s);
    }
}

// Kernel 2: build B' in MFMA-fragment order:
//   B'[((nt*8 + s)*64 + lane)] (short8) = V_j[n = nt*16 + (lane&15),
//                                             k = s*32 + (lane>>4)*8 + j]
// so k_main's B-fragment load is ONE contiguous coalesced 1 KB segment.
__global__ void k_vj(const float* __restrict__ V,
                     const float* __restrict__ noise,
                     const float* __restrict__ colsum,
                     unsigned short* __restrict__ Bp) {
    int t  = blockIdx.x * 256 + threadIdx.x;   // 0 .. 64*8*64-1 = 32767
    int nt = t >> 9;
    int s  = (t >> 6) & 7;
    int l  = t & 63;
    int lm = l & 15, lq = l >> 4;
    int n  = nt * 16 + lm;
    int k0 = s * 32 + lq * 8;
    union { short8 v; unsigned short us[8]; } pk;
    if (n < NTOP) {
        float cs = colsum[n];
        #pragma unroll
        for (int j = 0; j < 8; ++j) {
            int idx = n * KC + k0 + j;
            pk.us[j] = f2bf(V[idx] * cs + 0.1f * noise[idx]);
        }
    } else {
        #pragma unroll
        for (int j = 0; j < 8; ++j) pk.us[j] = 0;
    }
    reinterpret_cast<short8*>(Bp)[t] = pk.v;
}

// Kernel 3: fused U_emb + GEMM(A@B'^T) + sigmoid + masked Normal log-prob + reduce.
// Block = 256 threads = 4 waves, 16 M-rows shared (A rebuilt per wave, U L1-hot),
// each wave a disjoint quarter of N. B-frags are single coalesced 1KB loads.
__global__ __launch_bounds__(256, 4) void k_main(
    const float* __restrict__ U, const float* __restrict__ w5,
    const float* __restrict__ b1, const short8* __restrict__ Bf,
    const float* __restrict__ R, const int* __restrict__ C,
    float* __restrict__ out)
{
    const int tid  = threadIdx.x;
    const int wave = tid >> 6;
    const int l    = tid & 63;
    const int lm = l & 15;       // A row within tile / C-D n within tile
    const int lq = l >> 4;       // quad
    const int m0 = blockIdx.x << 4;

    const float w0 = w5[0], w1 = w5[1], w2 = w5[2], w3 = w5[3], w4 = w5[4];
    const float bb = b1[0];

    // ---- Build 8 A-fragments: U_emb[m0+lm, k] in bf16, k = s*32 + lq*8 + j ----
    short8 afr[8];
    {
        const int m = m0 + lm;
        #pragma unroll
        for (int s = 0; s < 8; ++s) {
            const float4* up4 = reinterpret_cast<const float4*>(
                U + (size_t)(m * KC + s * 32 + lq * 8) * 5);
            float u[40];
            #pragma unroll
            for (int i = 0; i < 10; ++i) {
                float4 t = up4[i];
                u[i*4+0] = t.x; u[i*4+1] = t.y; u[i*4+2] = t.z; u[i*4+3] = t.w;
            }
            union { short8 v; unsigned short us[8]; } pk;
            #pragma unroll
            for (int j = 0; j < 8; ++j) {
                float e = u[j*5+0]*w0 + u[j*5+1]*w1 + u[j*5+2]*w2
                        + u[j*5+3]*w3 + u[j*5+4]*w4 + bb;
                pk.us[j] = f2bf(e);
            }
            afr[s] = pk.v;
        }
    }

    float lpsum = 0.f;

    for (int ns = wave * 4; ns < wave * 4 + 4; ++ns) {
        const int n0 = ns << 6;
        f32x4 acc[4];
        #pragma unroll
        for (int t = 0; t < 4; ++t) acc[t] = (f32x4){0.f, 0.f, 0.f, 0.f};

        #pragma unroll
        for (int s = 0; s < 8; ++s) {
            #pragma unroll
            for (int t = 0; t < 4; ++t) {
                // fragment index: ((nt*8 + s)*64 + l), nt = ns*4 + t
                const short8 bfr = Bf[(((ns * 4 + t) * 8 + s) << 6) + l];
                acc[t] = __builtin_amdgcn_mfma_f32_16x16x32_bf16(afr[s], bfr, acc[t], 0, 0, 0);
            }
        }

        // Epilogue: C/D layout n = lane&15, m = (lane>>4)*4 + reg
        #pragma unroll
        for (int t = 0; t < 4; ++t) {
            const int n = n0 + t * 16 + lm;
            if (n < NTOP) {
                const size_t base = (size_t)(m0 + lq * 4) * NTOP + n;
                #pragma unroll
                for (int r = 0; r < 4; ++r) {
                    float x   = acc[t][r];
                    float muv = 1.f / (1.f + __expf(-x));
                    float d   = R[base + (size_t)r * NTOP] - muv;
                    float lp  = -50.f * d * d + 1.3836465597893728f;
                    if (C[base + (size_t)r * NTOP] == 1) lpsum += lp;
                }
            }
        }
    }

    #pragma unroll
    for (int off = 32; off > 0; off >>= 1) lpsum += __shfl_down(lpsum, off);
    if (l == 0) atomicAdd(out, lpsum);
}

extern "C" void kernel_launch(void* const* d_in, const int* in_sizes, int n_in,
                              void* d_out, int out_size, void* d_ws, size_t ws_size,
                              hipStream_t stream) {
    const float* V     = (const float*)d_in[1];
    const float* R     = (const float*)d_in[2];
    const float* nw    = (const float*)d_in[3];
    const float* U     = (const float*)d_in[4];
    const float* w5    = (const float*)d_in[5];
    const float* b1    = (const float*)d_in[6];
    const float* noise = (const float*)d_in[7];
    const int*   C     = (const int*)d_in[8];
    float* out = (float*)d_out;

    float* colsum  = (float*)d_ws;
    unsigned short* Bp = (unsigned short*)((char*)d_ws + 8192);

    hipMemsetAsync(colsum, 0, NTOP * sizeof(float), stream);
    hipMemsetAsync(out, 0, sizeof(float), stream);
    hipLaunchKernelGGL(k_prep, dim3(4, 125), dim3(256), 0, stream, nw, colsum);
    hipLaunchKernelGGL(k_vj, dim3(128), dim3(256), 0, stream,
                       V, noise, colsum, Bp);
    hipLaunchKernelGGL(k_main, dim3(MROWS / 16), dim3(256), 0, stream,
                       U, w5, b1, (const short8*)Bp, R, C, out);
}